// Round 1
// baseline (130.140 us; speedup 1.0000x reference)
//
#include <hip/hip_runtime.h>
#include <hip/hip_bf16.h>
#include <stdint.h>

#define N_NODES 8192
#define WORDS_PER_ROW 256   // 8192 / 32
#define H_DIM 64
#define NG 128              // NUM_GRAPHS

// ---- set adjacency bits: A[r,c] = 1 (set semantics via OR) ----
__global__ void edge_bits_kernel(const int* __restrict__ ei, int E,
                                 unsigned int* __restrict__ bitmap) {
    int k = blockIdx.x * blockDim.x + threadIdx.x;
    if (k >= E) return;
    int r = ei[k];
    int c = ei[E + k];
    atomicOr(&bitmap[(r << 8) + (c >> 5)], 1u << (c & 31));
}

// ---- dinv[i] = 1/sqrt(popcount(row i) + 1)  (row sum of A_p) ----
__global__ void dinv_kernel(const unsigned int* __restrict__ bitmap,
                            float* __restrict__ dinv) {
    int row  = (blockIdx.x << 2) + (threadIdx.x >> 6);
    int lane = threadIdx.x & 63;
    const uint4* brow = (const uint4*)(bitmap + (row << 8));
    uint4 v = brow[lane];                       // 4 words / lane, coalesced 1 KiB/row
    int c = __popc(v.x) + __popc(v.y) + __popc(v.z) + __popc(v.w);
    #pragma unroll
    for (int off = 32; off >= 1; off >>= 1) c += __shfl_xor(c, off, 64);
    if (lane == 0) dinv[row] = 1.0f / sqrtf((float)c + 1.0f);
}

// ---- layer-1 dense: out[i,f] = dinv_i * sum_k x[i,k] * th1[k,f]   (K=7) ----
__global__ void mm1_kernel(const float* __restrict__ x, const float* __restrict__ th,
                           const float* __restrict__ dinv, float* __restrict__ out) {
    __shared__ float sT[7 * 64];
    __shared__ float sX[4 * 7];
    int row0 = blockIdx.x << 2;
    for (int t = threadIdx.x; t < 7 * 64; t += 256) sT[t] = th[t];
    if (threadIdx.x < 28) sX[threadIdx.x] = x[row0 * 7 + threadIdx.x];
    __syncthreads();
    int r = threadIdx.x >> 6, f = threadIdx.x & 63;
    float acc = 0.f;
    #pragma unroll
    for (int k = 0; k < 7; ++k) acc = fmaf(sX[r * 7 + k], sT[(k << 6) + f], acc);
    int row = row0 + r;
    out[(row << 6) + f] = acc * dinv[row];
}

// ---- dense 64x64: out[i,f] = dinv_i * sum_k h[i,k] * th[k,f] ----
__global__ void mm64_kernel(const float* __restrict__ h, const float* __restrict__ th,
                            const float* __restrict__ dinv, float* __restrict__ out) {
    __shared__ float sT[64 * 64];
    __shared__ float sR[4 * 64];
    int row0 = blockIdx.x << 2;
    for (int t = threadIdx.x; t < 64 * 64; t += 256) sT[t] = th[t];
    sR[threadIdx.x] = h[(row0 << 6) + threadIdx.x];   // 4 rows, coalesced
    __syncthreads();
    int r = threadIdx.x >> 6, f = threadIdx.x & 63;
    float acc = 0.f;
    #pragma unroll
    for (int k = 0; k < 64; ++k) acc = fmaf(sR[(r << 6) + k], sT[(k << 6) + f], acc);
    int row = row0 + r;
    out[(row << 6) + f] = acc * dinv[row];
}

// ---- SpMM: y[i,:] = (relu?) dinv_i * ( ht[i,:] + sum_{bit(i,j)} ht[j,:] ) ----
// ht is prescaled by dinv_j; one wave per row, lane = feature.
template <int RELU>
__global__ void spmm_kernel(const unsigned int* __restrict__ bitmap,
                            const float* __restrict__ dinv,
                            const float* __restrict__ ht, float* __restrict__ out) {
    int row  = (blockIdx.x << 2) + (threadIdx.x >> 6);
    int lane = threadIdx.x & 63;
    const unsigned int* brow = bitmap + (row << 8);
    float acc = ht[(row << 6) + lane];          // eye term (already dinv_i * h_i)
    #pragma unroll
    for (int ch = 0; ch < 4; ++ch) {
        unsigned int w = brow[(ch << 6) + lane];
        unsigned long long mask = __ballot(w != 0u);
        while (mask) {
            int m = __ffsll(mask) - 1;
            mask &= mask - 1;
            unsigned int word = (unsigned int)__shfl((int)w, m, 64);
            int base = ((ch << 6) + m) << 5;
            while (word) {
                int b = __ffs(word) - 1;
                word &= word - 1;
                int j = base + b;
                acc += ht[(j << 6) + lane];     // coalesced 256B row gather
            }
        }
    }
    float res = acc * dinv[row];
    if (RELU) res = fmaxf(res, 0.f);
    out[(row << 6) + lane] = res;
}

// ---- segment-sum pooling via atomics ----
__global__ void pool_kernel(const float* __restrict__ h, const int* __restrict__ batch,
                            float* __restrict__ pooled, int* __restrict__ cnt) {
    int row  = (blockIdx.x << 2) + (threadIdx.x >> 6);
    int lane = threadIdx.x & 63;
    int g = batch[row];
    atomicAdd(&pooled[(g << 6) + lane], h[(row << 6) + lane]);
    if (lane == 0) atomicAdd(&cnt[g], 1);
}

// ---- out[g,c] = b[c] + sum_f relu(pooled[g,f]/cnt[g]) * W[f,c] ----
__global__ void final_kernel(const float* __restrict__ pooled, const int* __restrict__ cnt,
                             const float* __restrict__ W, const float* __restrict__ b,
                             float* __restrict__ out) {
    int g = threadIdx.x >> 1;
    int c = threadIdx.x & 1;
    int n = cnt[g]; if (n < 1) n = 1;
    float inv = 1.0f / (float)n;
    float acc = b[c];
    #pragma unroll
    for (int f = 0; f < 64; ++f) {
        float p = pooled[(g << 6) + f] * inv;
        p = fmaxf(p, 0.f);
        acc = fmaf(p, W[(f << 1) + c], acc);
    }
    out[(g << 1) + c] = acc;
}

extern "C" void kernel_launch(void* const* d_in, const int* in_sizes, int n_in,
                              void* d_out, int out_size, void* d_ws, size_t ws_size,
                              hipStream_t stream) {
    const float* x     = (const float*)d_in[0];
    const int*   ei    = (const int*)d_in[1];
    const int*   batch = (const int*)d_in[2];
    const float* th1   = (const float*)d_in[3];
    const float* th2   = (const float*)d_in[4];
    const float* th3   = (const float*)d_in[5];
    const float* W     = (const float*)d_in[6];
    const float* b     = (const float*)d_in[7];
    float* out = (float*)d_out;
    int E = in_sizes[1] / 2;

    char* ws = (char*)d_ws;
    unsigned int* bitmap = (unsigned int*)ws;                       // 8 MiB
    float* dinv  = (float*)(ws + (size_t)8 * 1024 * 1024);          // 32 KiB
    float* bufA  = (float*)(ws + (size_t)8 * 1024 * 1024 + 64 * 1024);  // 2 MiB
    float* bufB  = bufA + (size_t)N_NODES * H_DIM;                  // 2 MiB
    float* pooled = bufB + (size_t)N_NODES * H_DIM;                 // 32 KiB
    int*   cnt    = (int*)(pooled + NG * H_DIM);                    // 512 B

    hipMemsetAsync(bitmap, 0, (size_t)N_NODES * WORDS_PER_ROW * 4, stream);
    hipMemsetAsync(pooled, 0, (size_t)NG * H_DIM * 4 + NG * 4, stream);

    edge_bits_kernel<<<(E + 255) / 256, 256, 0, stream>>>(ei, E, bitmap);
    dinv_kernel<<<N_NODES / 4, 256, 0, stream>>>(bitmap, dinv);

    mm1_kernel<<<N_NODES / 4, 256, 0, stream>>>(x, th1, dinv, bufA);
    spmm_kernel<1><<<N_NODES / 4, 256, 0, stream>>>(bitmap, dinv, bufA, bufB);

    mm64_kernel<<<N_NODES / 4, 256, 0, stream>>>(bufB, th2, dinv, bufA);
    spmm_kernel<1><<<N_NODES / 4, 256, 0, stream>>>(bitmap, dinv, bufA, bufB);

    mm64_kernel<<<N_NODES / 4, 256, 0, stream>>>(bufB, th3, dinv, bufA);
    spmm_kernel<0><<<N_NODES / 4, 256, 0, stream>>>(bitmap, dinv, bufA, bufB);

    pool_kernel<<<N_NODES / 4, 256, 0, stream>>>(bufB, batch, pooled, cnt);
    final_kernel<<<1, 256, 0, stream>>>(pooled, cnt, W, b, out);
}

// Round 2
// 119.105 us; speedup vs baseline: 1.0927x; 1.0927x over previous
//
#include <hip/hip_runtime.h>
#include <hip/hip_bf16.h>
#include <stdint.h>

#define N_NODES 8192
#define WORDS_PER_ROW 256   // 8192 / 32
#define H_DIM 64
#define NG 128              // NUM_GRAPHS
#define MAXD 128            // max degree capacity (mean 32, Poisson; 128 is ~1e-50 safe)

// ---- set adjacency bits: A[r,c] = 1 (set semantics via OR) ----
__global__ void edge_bits_kernel(const int* __restrict__ ei, int E,
                                 unsigned int* __restrict__ bitmap) {
    int k = blockIdx.x * blockDim.x + threadIdx.x;
    if (k >= E) return;
    int r = ei[k];
    int c = ei[E + k];
    atomicOr(&bitmap[(r << 8) + (c >> 5)], 1u << (c & 31));
}

// ---- build CSR (ushort col ids) + dinv[i] = 1/sqrt(deg+1), one wave/row ----
__global__ void csr_kernel(const unsigned int* __restrict__ bitmap,
                           float* __restrict__ dinv,
                           unsigned short* __restrict__ cols,
                           int* __restrict__ nnz) {
    int row  = (blockIdx.x << 2) + (threadIdx.x >> 6);
    int lane = threadIdx.x & 63;
    const unsigned int* brow = bitmap + (row << 8);
    unsigned short* crow = cols + row * MAXD;
    int base = 0;
    #pragma unroll
    for (int ch = 0; ch < 4; ++ch) {
        unsigned int w = brow[(ch << 6) + lane];
        int c = __popc(w);
        // inclusive prefix sum of popcounts across 64 lanes
        int p = c;
        #pragma unroll
        for (int off = 1; off < 64; off <<= 1) {
            int t = __shfl_up(p, off, 64);
            if (lane >= off) p += t;
        }
        int pos = base + p - c;
        int cb = ((ch << 6) + lane) << 5;
        while (w) {
            int b = __ffs(w) - 1; w &= w - 1;
            crow[pos++] = (unsigned short)(cb + b);
        }
        base += __shfl(p, 63, 64);
    }
    if (lane == 0) {
        nnz[row]  = base;
        dinv[row] = 1.0f / sqrtf((float)base + 1.0f);
    }
}

// ---- layer-1 dense: out[i,f] = dinv_i * sum_k x[i,k] * th1[k,f]   (K=7) ----
__global__ void mm1_kernel(const float* __restrict__ x, const float* __restrict__ th,
                           const float* __restrict__ dinv, float* __restrict__ out) {
    __shared__ float sT[7 * 64];
    __shared__ float sX[4 * 7];
    int row0 = blockIdx.x << 2;
    for (int t = threadIdx.x; t < 7 * 64; t += 256) sT[t] = th[t];
    if (threadIdx.x < 28) sX[threadIdx.x] = x[row0 * 7 + threadIdx.x];
    __syncthreads();
    int r = threadIdx.x >> 6, f = threadIdx.x & 63;
    float acc = 0.f;
    #pragma unroll
    for (int k = 0; k < 7; ++k) acc = fmaf(sX[r * 7 + k], sT[(k << 6) + f], acc);
    int row = row0 + r;
    out[(row << 6) + f] = acc * dinv[row];
}

// ---- dense 64x64: out[i,f] = dinv_i * sum_k h[i,k] * th[k,f] ----
__global__ void mm64_kernel(const float* __restrict__ h, const float* __restrict__ th,
                            const float* __restrict__ dinv, float* __restrict__ out) {
    __shared__ float sT[64 * 64];
    __shared__ float sR[4 * 64];
    int row0 = blockIdx.x << 2;
    for (int t = threadIdx.x; t < 64 * 64; t += 256) sT[t] = th[t];
    sR[threadIdx.x] = h[(row0 << 6) + threadIdx.x];   // 4 rows, coalesced
    __syncthreads();
    int r = threadIdx.x >> 6, f = threadIdx.x & 63;
    float acc = 0.f;
    #pragma unroll
    for (int k = 0; k < 64; ++k) acc = fmaf(sR[(r << 6) + k], sT[(k << 6) + f], acc);
    int row = row0 + r;
    out[(row << 6) + f] = acc * dinv[row];
}

// ---- CSR SpMM: y[i,:] = (relu?) dinv_i * ( ht[i,:] + sum_j ht[j,:] ) ----
// ht prescaled by dinv_j. One wave per row, lane = feature.
// POOL: instead of writing y, atomically accumulate into pooled[batch[i]].
template <int RELU, int POOL>
__global__ void spmm_csr_kernel(const unsigned short* __restrict__ cols,
                                const int* __restrict__ nnz,
                                const float* __restrict__ dinv,
                                const float* __restrict__ ht,
                                float* __restrict__ out,
                                const int* __restrict__ batch,
                                float* __restrict__ pooled,
                                int* __restrict__ cnt) {
    int row  = (blockIdx.x << 2) + (threadIdx.x >> 6);
    int lane = threadIdx.x & 63;
    int n = nnz[row];
    const unsigned short* crow = cols + row * MAXD;
    int j0 = crow[lane];          // cooperative preload (within MAXD, always safe)
    int j1 = crow[64 + lane];
    float acc = ht[(row << 6) + lane];          // eye term (already dinv_i * h_i)
    for (int t = 0; t < n; ++t) {
        int j = __shfl((t < 64) ? j0 : j1, t & 63, 64);
        acc += ht[(j << 6) + lane];             // coalesced 256B row gather, L2-hit
    }
    float res = acc * dinv[row];
    if (RELU) res = fmaxf(res, 0.f);
    if (POOL) {
        int g = batch[row];
        atomicAdd(&pooled[(g << 6) + lane], res);
        if (lane == 0) atomicAdd(&cnt[g], 1);
    } else {
        out[(row << 6) + lane] = res;
    }
}

// ---- out[g,c] = b[c] + sum_f relu(pooled[g,f]/cnt[g]) * W[f,c] ----
__global__ void final_kernel(const float* __restrict__ pooled, const int* __restrict__ cnt,
                             const float* __restrict__ W, const float* __restrict__ b,
                             float* __restrict__ out) {
    int g = threadIdx.x >> 1;
    int c = threadIdx.x & 1;
    int n = cnt[g]; if (n < 1) n = 1;
    float inv = 1.0f / (float)n;
    float acc = b[c];
    #pragma unroll
    for (int f = 0; f < 64; ++f) {
        float p = pooled[(g << 6) + f] * inv;
        p = fmaxf(p, 0.f);
        acc = fmaf(p, W[(f << 1) + c], acc);
    }
    out[(g << 1) + c] = acc;
}

extern "C" void kernel_launch(void* const* d_in, const int* in_sizes, int n_in,
                              void* d_out, int out_size, void* d_ws, size_t ws_size,
                              hipStream_t stream) {
    const float* x     = (const float*)d_in[0];
    const int*   ei    = (const int*)d_in[1];
    const int*   batch = (const int*)d_in[2];
    const float* th1   = (const float*)d_in[3];
    const float* th2   = (const float*)d_in[4];
    const float* th3   = (const float*)d_in[5];
    const float* W     = (const float*)d_in[6];
    const float* b     = (const float*)d_in[7];
    float* out = (float*)d_out;
    int E = in_sizes[1] / 2;

    char* ws = (char*)d_ws;
    unsigned int*   bitmap = (unsigned int*)ws;                               // 8 MiB
    float*          dinv   = (float*)(ws + (size_t)8 * 1024 * 1024);          // 32 KiB
    int*            nnz    = (int*)(dinv + N_NODES);                          // 32 KiB
    unsigned short* cols   = (unsigned short*)(nnz + N_NODES);                // 2 MiB
    float*          bufA   = (float*)(cols + (size_t)N_NODES * MAXD);         // 2 MiB
    float*          bufB   = bufA + (size_t)N_NODES * H_DIM;                  // 2 MiB
    float*          pooled = bufB + (size_t)N_NODES * H_DIM;                  // 32 KiB
    int*            cnt    = (int*)(pooled + NG * H_DIM);                     // 512 B

    hipMemsetAsync(bitmap, 0, (size_t)N_NODES * WORDS_PER_ROW * 4, stream);
    hipMemsetAsync(pooled, 0, (size_t)NG * H_DIM * 4 + NG * 4, stream);

    edge_bits_kernel<<<(E + 255) / 256, 256, 0, stream>>>(ei, E, bitmap);
    csr_kernel<<<N_NODES / 4, 256, 0, stream>>>(bitmap, dinv, cols, nnz);

    mm1_kernel<<<N_NODES / 4, 256, 0, stream>>>(x, th1, dinv, bufA);
    spmm_csr_kernel<1, 0><<<N_NODES / 4, 256, 0, stream>>>(cols, nnz, dinv, bufA, bufB,
                                                           batch, pooled, cnt);
    mm64_kernel<<<N_NODES / 4, 256, 0, stream>>>(bufB, th2, dinv, bufA);
    spmm_csr_kernel<1, 0><<<N_NODES / 4, 256, 0, stream>>>(cols, nnz, dinv, bufA, bufB,
                                                           batch, pooled, cnt);
    mm64_kernel<<<N_NODES / 4, 256, 0, stream>>>(bufB, th3, dinv, bufA);
    spmm_csr_kernel<0, 1><<<N_NODES / 4, 256, 0, stream>>>(cols, nnz, dinv, bufA, bufB,
                                                           batch, pooled, cnt);
    final_kernel<<<1, 256, 0, stream>>>(pooled, cnt, W, b, out);
}